// Round 10
// baseline (2600.807 us; speedup 1.0000x reference)
//
#include <hip/hip_runtime.h>

#define WAVE 64

// ---------------------------------------------------------------------------
// init: split pointcloud (B,N,6) -> xyz + feats, AND zero stats+fps slots
// (fused r10: was split_kernel + zero_kernel, -1 dispatch)
__global__ __launch_bounds__(256) void init_kernel(const float* __restrict__ pc,
    float* __restrict__ xyz, float* __restrict__ feats, float* __restrict__ zbase,
    int nsplit, int nzero) {
  int t = blockIdx.x * blockDim.x + threadIdx.x;
  if (t < nsplit) {
    const float* p = pc + (size_t)t * 6;
    xyz[t * 3 + 0] = p[0]; xyz[t * 3 + 1] = p[1]; xyz[t * 3 + 2] = p[2];
    feats[t * 3 + 0] = p[3]; feats[t * 3 + 1] = p[4]; feats[t * 3 + 2] = p[5];
  }
  if (t < nzero) zbase[t] = 0.f;
}

// ---------------------------------------------------------------------------
// Monotone float <-> u32 mapping (radix-sort trick): unsigned order == float
// order for all non-NaN values. Used for LDS atomicMax/Min on f32 extrema.
__device__ __forceinline__ unsigned mapf(float f) {
  unsigned b = __float_as_uint(f);
  return (b & 0x80000000u) ? ~b : (b | 0x80000000u);
}
__device__ __forceinline__ float unmapf(unsigned u) {
  unsigned b = (u & 0x80000000u) ? (u ^ 0x80000000u) : ~u;
  return __uint_as_float(b);
}

// ---------------------------------------------------------------------------
// Fused 64-bit wave max via DPP (rocPRIM row_shr 1/2/4/8 + row_bcast15/31).
__device__ __forceinline__ unsigned long long dpp_max_u64(unsigned long long v) {
#define DPP_STEP_U64(ctrl) { \
    unsigned lo_ = (unsigned)v, hi_ = (unsigned)(v >> 32); \
    unsigned tlo_ = (unsigned)__builtin_amdgcn_update_dpp((int)lo_, (int)lo_, ctrl, 0xf, 0xf, false); \
    unsigned thi_ = (unsigned)__builtin_amdgcn_update_dpp((int)hi_, (int)hi_, ctrl, 0xf, 0xf, false); \
    unsigned long long t_ = ((unsigned long long)thi_ << 32) | tlo_; \
    if (t_ > v) v = t_; }
  DPP_STEP_U64(0x111) DPP_STEP_U64(0x112) DPP_STEP_U64(0x114)
  DPP_STEP_U64(0x118) DPP_STEP_U64(0x142) DPP_STEP_U64(0x143)
#undef DPP_STEP_U64
  return v;  // valid in lane 63
}

// ---------------------------------------------------------------------------
// FPS, layer 0 — r5 protocol, at its measured floor (~1272us). FROZEN.
// (r8 poll-pipelining null => residual is publish->cross-XCD visibility.)
#define FPS_W   8
#define FPS_PT  8      // points per thread (2048 per WG / 256 threads)
__global__ __launch_bounds__(256, 4) void fps_big_multi_kernel(
    const float* __restrict__ xyz, float* __restrict__ new_xyz,
    unsigned long long* __restrict__ gkey, int N, int S) {
  const int b = blockIdx.x & 7;           // same-XCD heuristic for a batch
  const int w = blockIdx.x >> 3;          // WG within batch, 0..7
  const int tid = threadIdx.x;
  const int lane = tid & 63;
  const int wv = tid >> 6;                // wave within WG, 0..3
  const float* px = xyz + (size_t)b * N * 3;
  const int base = w * (FPS_PT * 256);
  __shared__ unsigned long long s_cand[4];
  __shared__ unsigned long long s_win;
  float rx[FPS_PT], ry[FPS_PT], rz[FPS_PT], mind[FPS_PT];
#pragma unroll
  for (int p = 0; p < FPS_PT; ++p) {
    int i = base + p * 256 + tid;
    rx[p] = px[i * 3 + 0]; ry[p] = px[i * 3 + 1]; rz[p] = px[i * 3 + 2];
    asm volatile("" : "+v"(rx[p]), "+v"(ry[p]), "+v"(rz[p]));
    mind[p] = 1e10f;
  }
  float qx = px[0], qy = px[1], qz = px[2];   // pick 0 is always index 0
  if (w == 0 && tid == 0) {
    float* o = new_xyz + (size_t)b * S * 3;
    o[0] = qx; o[1] = qy; o[2] = qz;
  }
  unsigned long long* slots = gkey + (size_t)b * S * FPS_W;
  for (unsigned it = 1; it < (unsigned)S; ++it) {
    float bestv = -1.f; unsigned besti = 0;
#pragma unroll
    for (int p = 0; p < FPS_PT; ++p) {
      float dx = __fsub_rn(rx[p], qx);
      float dy = __fsub_rn(ry[p], qy);
      float dz = __fsub_rn(rz[p], qz);
      float d = __fadd_rn(__fadd_rn(__fmul_rn(dx, dx), __fmul_rn(dy, dy)), __fmul_rn(dz, dz));
      float mo = fminf(mind[p], d);
      mind[p] = mo;
      // p ascending => index ascending within thread: keeps first max on ties
      if (mo > bestv) { bestv = mo; besti = (unsigned)(base + p * 256 + tid); }
    }
    unsigned long long key = ((unsigned long long)__float_as_uint(bestv) << 32)
                           | (0xFFFFFFFFu - besti);
    key = dpp_max_u64(key);
    if (lane == 63) s_cand[wv] = key;       // plain LDS store, one per wave
    __syncthreads();
    if (tid < 64) {
      unsigned long long k = s_cand[lane & 3];
#pragma unroll
      for (int off = 1; off < 4; off <<= 1) {   // every lane -> WG winner
        unsigned long long o = __shfl_xor(k, off, 4);
        if (o > k) k = o;
      }
      if (lane == 0) {
        // publish this WG's winner (nonzero); fire-and-forget atomic
        atomicExch(&slots[(size_t)it * FPS_W + w], k);
      }
      unsigned long long kk = 0ull;
      if (lane < FPS_W) {
        unsigned long long* sl = &slots[(size_t)it * FPS_W + lane];
        unsigned long long t0 = __builtin_amdgcn_s_memrealtime();
        int r = 0;
        for (;;) {
          kk = __hip_atomic_load(sl, __ATOMIC_RELAXED, __HIP_MEMORY_SCOPE_AGENT);
          if (kk) break;
          if (++r > 256) {                  // slow path: coherence insurance
            kk = atomicMax(sl, 0ull);
            if (kk) break;
            if (__builtin_amdgcn_s_memrealtime() - t0 > 2000000ull) {
              kk = 0xFFFFFFFFull;           // dist 0: loses to any real key
              break;
            }
            __builtin_amdgcn_s_sleep(1);
          }
        }
      }
#pragma unroll
      for (int off = 1; off < FPS_W; off <<= 1) {
        unsigned long long o = __shfl_xor(kk, off, FPS_W);
        if (o > kk) kk = o;
      }
      if (lane == 0) s_win = kk;
    }
    __syncthreads();
    unsigned long long k = s_win;
    int last = (int)((0xFFFFFFFFu - (unsigned)k) & 16383u);
    const float* q = px + (size_t)last * 3;  // broadcast L2 load
    qx = q[0]; qy = q[1]; qz = q[2];
    if (w == 0 && tid == 0) {
      float* o = new_xyz + ((size_t)b * S + it) * 3;
      o[0] = qx; o[1] = qy; o[2] = qz;
    }
  }
}

// ---------------------------------------------------------------------------
// FPS chain, layers 1-3 in ONE kernel (r10: -2 dispatches). The chain
// fps1->fps2->fps3 depends only on centers, produced by the SAME batch-WG:
// phase ph reads srcs[ph] (= previous phase's dst, same-CU caches + barrier
// => coherent) and runs the r7-verified parity-buffered body. Inactive waves
// (wv >= N/64) skip compute but hit every barrier. Key lattice unchanged ->
// bit-identical pick sequence to the r7 fps_small kernels.
__global__ __launch_bounds__(1024) void fps_chain_kernel(
    const float* __restrict__ p1, float* __restrict__ p2,
    float* __restrict__ p3, float* __restrict__ p4) {
  const int b = blockIdx.x;
  const int tid = threadIdx.x;
  const int lane = tid & 63;
  const int wv = tid >> 6;
  __shared__ float sx[1024], sy[1024], sz[1024];
  __shared__ unsigned long long s_cand[2][16];
  const float* srcs[3]; float* dsts[3];
  srcs[0] = p1; srcs[1] = p2; srcs[2] = p3;
  dsts[0] = p2; dsts[1] = p3; dsts[2] = p4;
  const int Np[3] = {1024, 256, 64};
  const int Sp[3] = {256, 64, 16};
  for (int ph = 0; ph < 3; ++ph) {
    const int N = Np[ph], S = Sp[ph], NW = N >> 6;
    const float* px = srcs[ph] + (size_t)b * N * 3;
    float* dst = dsts[ph] + (size_t)b * S * 3;
    float x = 0.f, y = 0.f, z = 0.f, mind = 1e10f;
    if (tid < N) {
      x = px[tid * 3 + 0]; y = px[tid * 3 + 1]; z = px[tid * 3 + 2];
      sx[tid] = x; sy[tid] = y; sz[tid] = z;
    }
    float qx = px[0], qy = px[1], qz = px[2];
    if (tid == 0) { dst[0] = qx; dst[1] = qy; dst[2] = qz; }
    __syncthreads();
    for (unsigned it = 1; it < (unsigned)S; ++it) {
      if (wv < NW) {
        float dx = __fsub_rn(x, qx);
        float dy = __fsub_rn(y, qy);
        float dz = __fsub_rn(z, qz);
        float d = __fadd_rn(__fadd_rn(__fmul_rn(dx, dx), __fmul_rn(dy, dy)), __fmul_rn(dz, dz));
        mind = fminf(mind, d);
        unsigned long long key = ((unsigned long long)__float_as_uint(mind) << 32)
                               | (0xFFFFFFFFu - (unsigned)tid);
        key = dpp_max_u64(key);
        if (lane == 63) s_cand[it & 1u][wv] = key;
      }
      __syncthreads();                      // the ONLY barrier per iteration
      if (wv < NW) {
        unsigned long long k = (lane < NW) ? s_cand[it & 1u][lane] : 0ull;
        k = dpp_max_u64(k);
        unsigned klo = (unsigned)__builtin_amdgcn_readlane((int)(unsigned)k, 63);
        int last = (int)(0xFFFFFFFFu - klo);
        qx = sx[last]; qy = sy[last]; qz = sz[last];   // LDS broadcast
        if (tid == 0) {
          float* o = dst + (size_t)it * 3;
          o[0] = qx; o[1] = qy; o[2] = qz;
        }
      }
    }
    __syncthreads();                        // phase boundary
  }
}

// ---------------------------------------------------------------------------
// Fused tiled f32 GEMM: Y(RxCo) = normReLU(A)(RxC) @ W(CxCo).
//  - GATHER MODE (gather != 0; j0): r10 — the per-group ball query itself is
//    fused in (verbatim wave-per-group algorithm, results in LDS s_idx; no
//    ballidx buffer, no separate dispatch). Then A is built on the fly from
//    [xyz[j]-center, feats[j]] (bit-identical expressions). grid.y>1 blocks
//    recompute the (tiny, deterministic) query.
//  - EXTREMA MODE (extmax != nullptr; j2): Y not written; per-group max AND
//    min of raw y -> monotone-mapped u32 LDS atomics -> global (G x Co).
//    f(y)=gamma*((y-mu)*rs)+beta is monotone in y => final pass picks
//    max/min by sign(gamma). Bit-exact (r9-verified).
//  - r10: inner K loop bounded by kmax = min(BK, C-k0); skipped terms add
//    exactly +-0 => output-identical (zero-padded columns).
// R % 64 == 0 always; C/Co guarded.
#define BM 64
#define BN 64
#define BK 16
__global__ __launch_bounds__(256) void mm_fused_kernel(const float* __restrict__ A,
    const float* __restrict__ W, float* __restrict__ Y,
    float* __restrict__ st_out, const float* __restrict__ st_in,
    const float* __restrict__ g_in, const float* __restrict__ b_in,
    int R, int C, int Co, float inv_n,
    int gather, const float* __restrict__ xyz,
    const float* __restrict__ feats, const float* __restrict__ centers,
    int N, int kshift, int sshift, int ci, float r2,
    unsigned* __restrict__ extmax, unsigned* __restrict__ extmin) {
  __shared__ float As[BK][BM + 4];
  __shared__ float Bs[BK][BN + 4];
  __shared__ float s_mu[260], s_rs[260], s_g[260], s_b[260];
  __shared__ float s_sum[BN], s_sq[BN];
  __shared__ int s_idx[BM];
  __shared__ unsigned s_mx[4][BN], s_mn[4][BN];
  int r0 = blockIdx.x * BM;
  int n0 = blockIdx.y * BN;
  int tid = threadIdx.x;
  int tx = tid & 15, ty = tid >> 4;
  if (st_in) {
    for (int c = tid; c < C; c += 256) {
      float mu = st_in[c] * inv_n;
      float var = st_in[512 + c] * inv_n - mu * mu;
      s_mu[c] = mu; s_rs[c] = rsqrtf(var + 1e-5f);
      s_g[c] = g_in[c]; s_b[c] = b_in[c];
    }
  }
  if (gather) {
    // fused ball query: wave wv handles local group wv (verbatim algorithm)
    int wvq = tid >> 6, ln = tid & 63;
    int gpb = BM >> kshift;               // groups per block (2 or 4)
    if (wvq < gpb) {
      int G = (r0 >> kshift) + wvq;
      int bb = G >> sshift;
      const float* px = xyz + (size_t)bb * N * 3;
      float cx = centers[(size_t)G * 3 + 0];
      float cy = centers[(size_t)G * 3 + 1];
      float cz = centers[(size_t)G * 3 + 2];
      int Kn = 1 << kshift;
      int cnt = 0, firsti = 0;
      for (int bs = 0; bs < N; bs += WAVE) {
        int i = bs + ln;
        float dx = __fsub_rn(cx, px[i * 3 + 0]);
        float dy = __fsub_rn(cy, px[i * 3 + 1]);
        float dz = __fsub_rn(cz, px[i * 3 + 2]);
        float d = __fadd_rn(__fadd_rn(__fmul_rn(dx, dx), __fmul_rn(dy, dy)), __fmul_rn(dz, dz));
        bool hit = d < r2;
        unsigned long long m = __ballot(hit);
        if (hit) {
          int slot = cnt + __popcll(m & ((1ull << ln) - 1ull));
          if (slot < Kn) s_idx[(wvq << kshift) + slot] = i;
        }
        if (cnt == 0 && m) firsti = bs + __ffsll((unsigned long long)m) - 1;
        cnt += __popcll(m);
        if (cnt >= Kn) break;
      }
      for (int q = cnt + ln; q < Kn; q += WAVE) s_idx[(wvq << kshift) + q] = firsti;
    }
  }
  if (tid < BN) { s_sum[tid] = 0.f; s_sq[tid] = 0.f; }
  if (extmax) {
    for (int t2 = tid; t2 < 4 * BN; t2 += 256) {
      ((unsigned*)s_mx)[t2] = 0u;            // < mapf(any finite/inf)
      ((unsigned*)s_mn)[t2] = 0xFFFFFFFFu;   // > mapf(any finite/inf)
    }
  }
  __syncthreads();
  float acc[4][4] = {};
  for (int k0 = 0; k0 < C; k0 += BK) {
#pragma unroll
    for (int u = 0; u < 4; ++u) {
      int lin = tid + u * 256;
      int row = lin >> 4;
      int cc = lin & 15;
      int c = k0 + cc;
      float v = 0.f;
      if (c < C) {
        if (gather) {
          int r = r0 + row;
          int g = r >> kshift;
          int bb = g >> sshift;
          int j = s_idx[row];
          if (c < 3) v = __fsub_rn(xyz[((size_t)bb * N + j) * 3 + c],
                                   centers[(size_t)g * 3 + c]);
          else       v = feats[((size_t)bb * N + j) * ci + (c - 3)];
        } else {
          v = A[(size_t)(r0 + row) * C + c];
          if (st_in) {
            v = s_g[c] * ((v - s_mu[c]) * s_rs[c]) + s_b[c];
            v = v > 0.f ? v : 0.f;
          }
        }
      }
      As[cc][row] = v;
    }
#pragma unroll
    for (int u = 0; u < 4; ++u) {
      int lin = tid + u * 256;
      int kk = lin >> 6;
      int n = lin & 63;
      int c = k0 + kk;
      Bs[kk][n] = (c < C && (n0 + n) < Co) ? W[(size_t)c * Co + n0 + n] : 0.f;
    }
    __syncthreads();
    int kmax = C - k0; if (kmax > BK) kmax = BK;
    if (kmax == BK) {
#pragma unroll
      for (int kk = 0; kk < BK; ++kk) {
        float a0[4], b0[4];
#pragma unroll
        for (int i = 0; i < 4; ++i) a0[i] = As[kk][ty * 4 + i];
#pragma unroll
        for (int jj = 0; jj < 4; ++jj) b0[jj] = Bs[kk][tx * 4 + jj];
#pragma unroll
        for (int i = 0; i < 4; ++i)
#pragma unroll
          for (int jj = 0; jj < 4; ++jj)
            acc[i][jj] = fmaf(a0[i], b0[jj], acc[i][jj]);
      }
    } else {
      for (int kk = 0; kk < kmax; ++kk) {
        float a0[4], b0[4];
#pragma unroll
        for (int i = 0; i < 4; ++i) a0[i] = As[kk][ty * 4 + i];
#pragma unroll
        for (int jj = 0; jj < 4; ++jj) b0[jj] = Bs[kk][tx * 4 + jj];
#pragma unroll
        for (int i = 0; i < 4; ++i)
#pragma unroll
          for (int jj = 0; jj < 4; ++jj)
            acc[i][jj] = fmaf(a0[i], b0[jj], acc[i][jj]);
      }
    }
    __syncthreads();
  }
  if (!extmax) {
#pragma unroll
    for (int i = 0; i < 4; ++i) {
      int r = r0 + ty * 4 + i;
#pragma unroll
      for (int jj = 0; jj < 4; ++jj) {
        int n = n0 + tx * 4 + jj;
        if (n < Co) Y[(size_t)r * Co + n] = acc[i][jj];
      }
    }
  } else {
    // per-group extrema: this thread's 4 rows (ty*4..+3) lie in ONE group
    int gi = (ty * 4) >> kshift;
#pragma unroll
    for (int jj = 0; jj < 4; ++jj) {
      float mx = acc[0][jj], mn = acc[0][jj];
#pragma unroll
      for (int i = 1; i < 4; ++i) {
        mx = fmaxf(mx, acc[i][jj]); mn = fminf(mn, acc[i][jj]);
      }
      atomicMax(&s_mx[gi][tx * 4 + jj], mapf(mx));
      atomicMin(&s_mn[gi][tx * 4 + jj], mapf(mn));
    }
  }
  // epilogue: per-column sum/sumsq of this block's tile -> LDS -> global
#pragma unroll
  for (int jj = 0; jj < 4; ++jj) {
    float cs = 0.f, cq = 0.f;
#pragma unroll
    for (int i = 0; i < 4; ++i) { float v = acc[i][jj]; cs += v; cq += v * v; }
    atomicAdd(&s_sum[tx * 4 + jj], cs);
    atomicAdd(&s_sq[tx * 4 + jj], cq);
  }
  __syncthreads();
  if (tid < BN) {
    int n = n0 + tid;
    if (n < Co) {
      atomicAdd(&st_out[n], s_sum[tid]);
      atomicAdd(&st_out[512 + n], s_sq[tid]);
    }
  }
  if (extmax) {
    int gpb = BM >> kshift;               // groups per block (2 or 4)
    if (tid < gpb * BN) {
      int gi = tid >> 6;
      int n = tid & 63;
      if (n0 + n < Co) {
        size_t o = (size_t)((r0 >> kshift) + gi) * Co + n0 + n;
        extmax[o] = s_mx[gi][n];
        extmin[o] = s_mn[gi][n];
      }
    }
  }
}

// Final pass: normalize the pre-reduced group extremum and relu. Slope of
// f(y)=gamma*((y-mu)*rs)+beta is sign(gamma) (rs>0): pick max for gamma>=0,
// min otherwise. Bit-exact vs per-element normalize-then-max (monotonicity).
__global__ __launch_bounds__(256) void norm_max_final_kernel(
    const unsigned* __restrict__ extmax, const unsigned* __restrict__ extmin,
    float* __restrict__ O, const float* __restrict__ st,
    const float* __restrict__ gamma, const float* __restrict__ beta,
    int total, int Co, float inv_n) {
  int t = blockIdx.x * blockDim.x + threadIdx.x;
  if (t >= total) return;
  int c = t & (Co - 1);
  float mu = st[c] * inv_n;
  float var = st[512 + c] * inv_n - mu * mu;
  float rs = rsqrtf(var + 1e-5f);
  float ga = gamma[c], be = beta[c];
  float y = (ga >= 0.f) ? unmapf(extmax[t]) : unmapf(extmin[t]);
  float v = ga * ((y - mu) * rs) + be;
  O[t] = v > 0.f ? v : 0.f;
}

// ---------------------------------------------------------------------------
extern "C" void kernel_launch(void* const* d_in, const int* in_sizes, int n_in,
                              void* d_out, int out_size, void* d_ws, size_t ws_size,
                              hipStream_t stream) {
  const float* pc = (const float*)d_in[0];
  float* out = (float*)d_out;
  char* wsb = (char*)d_ws;

  // ws layout: [1MB,+48KB) stats; [2MB,+512KB) fps slots; [3MB,5MB) extmax;
  //            [5MB,7MB) extmin; [8MB,42MB) bufA; [42MB,76MB) bufB
  float* stats = (float*)(wsb + ((size_t)1 << 20));
  unsigned long long* gkey = (unsigned long long*)(wsb + ((size_t)2 << 20));
  unsigned* extmax = (unsigned*)(wsb + ((size_t)3 << 20));
  unsigned* extmin = (unsigned*)(wsb + ((size_t)5 << 20));
  float* bufA = (float*)(wsb + ((size_t)8 << 20));
  float* bufB = (float*)(wsb + ((size_t)42 << 20));

  const int B = 8;
  static const int Ns[4] = {16384, 1024, 256, 64};
  static const int Ss[4] = {1024, 256, 64, 16};
  static const int Ks[4] = {32, 32, 16, 16};
  static const int Ksh[4] = {5, 5, 4, 4};     // log2(K)
  static const int Ssh[4] = {10, 8, 6, 4};    // log2(S)
  static const double Rr[4] = {0.02, 0.04, 0.06, 0.08};
  static const int Ci[4] = {3, 64, 128, 256};
  static const int mlp[4][4] = {{6,32,32,64},{67,64,64,128},{131,128,128,256},{259,256,256,512}};
  static const size_t ox[5] = {0, 393216, 417792, 423936, 425472};
  static const size_t of[5] = {425856, 819072, 1343360, 1605504, 1736576};

  // split (131072 threads' worth) + zero stats/slots ([1MB,3MB) = 524288 f32)
  init_kernel<<<(524288 + 255) / 256, 256, 0, stream>>>(pc, out + ox[0], out + of[0],
                                                        stats, B * 16384, 524288);
  fps_big_multi_kernel<<<B * FPS_W, 256, 0, stream>>>(out + ox[0], out + ox[1], gkey,
                                                      16384, 1024);
  // FPS chain L1->L2->L3 (depends only on centers0)
  fps_chain_kernel<<<B, 1024, 0, stream>>>(out + ox[1], out + ox[2], out + ox[3], out + ox[4]);

  for (int l = 0; l < 4; ++l) {
    const float* xyz = out + ox[l];
    const float* fts = out + of[l];
    float* nxyz = out + ox[l + 1];
    const int N = Ns[l], S = Ss[l], ci = Ci[l];
    const float r2 = (float)(Rr[l] * Rr[l]);

    const int R = B * S * Ks[l];
    const float inv_n = 1.0f / (float)R;
    float* X = bufA; float* Y = bufB;
    const float* prev_st = nullptr;
    const float* prev_g = nullptr;
    const float* prev_b = nullptr;
    for (int j = 0; j < 3; ++j) {
      const int cin = mlp[l][j], cout = mlp[l][j + 1];
      const float* Wt = (const float*)d_in[1 + (l * 3 + j) * 3 + 0];
      const float* Ga = (const float*)d_in[1 + (l * 3 + j) * 3 + 1];
      const float* Be = (const float*)d_in[1 + (l * 3 + j) * 3 + 2];
      float* st = stats + (size_t)(l * 3 + j) * 1024;
      const bool last = (j == 2);
      dim3 grid(R / 64, (cout + 63) / 64);
      mm_fused_kernel<<<grid, 256, 0, stream>>>(
          (j == 0) ? nullptr : X, Wt, last ? nullptr : Y, st,
          prev_st, prev_g, prev_b, R, cin, cout, inv_n,
          (j == 0) ? 1 : 0, xyz, fts, nxyz,
          N, Ksh[l], Ssh[l], ci, r2,
          last ? extmax : nullptr, last ? extmin : nullptr);
      if (!last) {
        prev_st = st; prev_g = Ga; prev_b = Be;
        float* tswap = X; X = Y; Y = tswap;
      } else {
        int G = B * S;
        int tot = G * cout;
        norm_max_final_kernel<<<(tot + 255) / 256, 256, 0, stream>>>(
            extmax, extmin, out + of[l + 1], st, Ga, Be, tot, cout, inv_n);
      }
    }
  }
}

// Round 11
// 2403.057 us; speedup vs baseline: 1.0823x; 1.0823x over previous
//
#include <hip/hip_runtime.h>

#define WAVE 64

// ---------------------------------------------------------------------------
// init: split pointcloud (B,N,6) -> xyz + feats, AND zero stats+fps slots
// (r10-verified-safe fusion of split_kernel + zero_kernel, -1 dispatch)
__global__ __launch_bounds__(256) void init_kernel(const float* __restrict__ pc,
    float* __restrict__ xyz, float* __restrict__ feats, float* __restrict__ zbase,
    int nsplit, int nzero) {
  int t = blockIdx.x * blockDim.x + threadIdx.x;
  if (t < nsplit) {
    const float* p = pc + (size_t)t * 6;
    xyz[t * 3 + 0] = p[0]; xyz[t * 3 + 1] = p[1]; xyz[t * 3 + 2] = p[2];
    feats[t * 3 + 0] = p[3]; feats[t * 3 + 1] = p[4]; feats[t * 3 + 2] = p[5];
  }
  if (t < nzero) zbase[t] = 0.f;
}

// ---------------------------------------------------------------------------
// Monotone float <-> u32 mapping (radix-sort trick): unsigned order == float
// order for all non-NaN values. Used for LDS atomicMax/Min on f32 extrema.
__device__ __forceinline__ unsigned mapf(float f) {
  unsigned b = __float_as_uint(f);
  return (b & 0x80000000u) ? ~b : (b | 0x80000000u);
}
__device__ __forceinline__ float unmapf(unsigned u) {
  unsigned b = (u & 0x80000000u) ? (u ^ 0x80000000u) : ~u;
  return __uint_as_float(b);
}

// ---------------------------------------------------------------------------
// Fused 64-bit wave max via DPP (rocPRIM row_shr 1/2/4/8 + row_bcast15/31).
__device__ __forceinline__ unsigned long long dpp_max_u64(unsigned long long v) {
#define DPP_STEP_U64(ctrl) { \
    unsigned lo_ = (unsigned)v, hi_ = (unsigned)(v >> 32); \
    unsigned tlo_ = (unsigned)__builtin_amdgcn_update_dpp((int)lo_, (int)lo_, ctrl, 0xf, 0xf, false); \
    unsigned thi_ = (unsigned)__builtin_amdgcn_update_dpp((int)hi_, (int)hi_, ctrl, 0xf, 0xf, false); \
    unsigned long long t_ = ((unsigned long long)thi_ << 32) | tlo_; \
    if (t_ > v) v = t_; }
  DPP_STEP_U64(0x111) DPP_STEP_U64(0x112) DPP_STEP_U64(0x114)
  DPP_STEP_U64(0x118) DPP_STEP_U64(0x142) DPP_STEP_U64(0x143)
#undef DPP_STEP_U64
  return v;  // valid in lane 63
}

// ---------------------------------------------------------------------------
// FPS, layer 0 — r5 protocol, at its measured floor (~1272us). FROZEN.
// (r8 poll-pipelining null => residual is publish->cross-XCD visibility;
//  r6 L2-warm/multi-poller and r4 32-publisher variants all regressed.)
#define FPS_W   8
#define FPS_PT  8      // points per thread (2048 per WG / 256 threads)
__global__ __launch_bounds__(256, 4) void fps_big_multi_kernel(
    const float* __restrict__ xyz, float* __restrict__ new_xyz,
    unsigned long long* __restrict__ gkey, int N, int S) {
  const int b = blockIdx.x & 7;           // same-XCD heuristic for a batch
  const int w = blockIdx.x >> 3;          // WG within batch, 0..7
  const int tid = threadIdx.x;
  const int lane = tid & 63;
  const int wv = tid >> 6;                // wave within WG, 0..3
  const float* px = xyz + (size_t)b * N * 3;
  const int base = w * (FPS_PT * 256);
  __shared__ unsigned long long s_cand[4];
  __shared__ unsigned long long s_win;
  float rx[FPS_PT], ry[FPS_PT], rz[FPS_PT], mind[FPS_PT];
#pragma unroll
  for (int p = 0; p < FPS_PT; ++p) {
    int i = base + p * 256 + tid;
    rx[p] = px[i * 3 + 0]; ry[p] = px[i * 3 + 1]; rz[p] = px[i * 3 + 2];
    asm volatile("" : "+v"(rx[p]), "+v"(ry[p]), "+v"(rz[p]));
    mind[p] = 1e10f;
  }
  float qx = px[0], qy = px[1], qz = px[2];   // pick 0 is always index 0
  if (w == 0 && tid == 0) {
    float* o = new_xyz + (size_t)b * S * 3;
    o[0] = qx; o[1] = qy; o[2] = qz;
  }
  unsigned long long* slots = gkey + (size_t)b * S * FPS_W;
  for (unsigned it = 1; it < (unsigned)S; ++it) {
    float bestv = -1.f; unsigned besti = 0;
#pragma unroll
    for (int p = 0; p < FPS_PT; ++p) {
      float dx = __fsub_rn(rx[p], qx);
      float dy = __fsub_rn(ry[p], qy);
      float dz = __fsub_rn(rz[p], qz);
      float d = __fadd_rn(__fadd_rn(__fmul_rn(dx, dx), __fmul_rn(dy, dy)), __fmul_rn(dz, dz));
      float mo = fminf(mind[p], d);
      mind[p] = mo;
      // p ascending => index ascending within thread: keeps first max on ties
      if (mo > bestv) { bestv = mo; besti = (unsigned)(base + p * 256 + tid); }
    }
    unsigned long long key = ((unsigned long long)__float_as_uint(bestv) << 32)
                           | (0xFFFFFFFFu - besti);
    key = dpp_max_u64(key);
    if (lane == 63) s_cand[wv] = key;       // plain LDS store, one per wave
    __syncthreads();
    if (tid < 64) {
      unsigned long long k = s_cand[lane & 3];
#pragma unroll
      for (int off = 1; off < 4; off <<= 1) {   // every lane -> WG winner
        unsigned long long o = __shfl_xor(k, off, 4);
        if (o > k) k = o;
      }
      if (lane == 0) {
        // publish this WG's winner (nonzero); fire-and-forget atomic
        atomicExch(&slots[(size_t)it * FPS_W + w], k);
      }
      unsigned long long kk = 0ull;
      if (lane < FPS_W) {
        unsigned long long* sl = &slots[(size_t)it * FPS_W + lane];
        unsigned long long t0 = __builtin_amdgcn_s_memrealtime();
        int r = 0;
        for (;;) {
          kk = __hip_atomic_load(sl, __ATOMIC_RELAXED, __HIP_MEMORY_SCOPE_AGENT);
          if (kk) break;
          if (++r > 256) {                  // slow path: coherence insurance
            kk = atomicMax(sl, 0ull);
            if (kk) break;
            if (__builtin_amdgcn_s_memrealtime() - t0 > 2000000ull) {
              kk = 0xFFFFFFFFull;           // dist 0: loses to any real key
              break;
            }
            __builtin_amdgcn_s_sleep(1);
          }
        }
      }
#pragma unroll
      for (int off = 1; off < FPS_W; off <<= 1) {
        unsigned long long o = __shfl_xor(kk, off, FPS_W);
        if (o > kk) kk = o;
      }
      if (lane == 0) s_win = kk;
    }
    __syncthreads();
    unsigned long long k = s_win;
    int last = (int)((0xFFFFFFFFu - (unsigned)k) & 16383u);
    const float* q = px + (size_t)last * 3;  // broadcast L2 load
    qx = q[0]; qy = q[1]; qz = q[2];
    if (w == 0 && tid == 0) {
      float* o = new_xyz + ((size_t)b * S + it) * 3;
      o[0] = qx; o[1] = qy; o[2] = qz;
    }
  }
}

// ---------------------------------------------------------------------------
// FPS, layers 1-3 — lean combine (r7/r9-verified): per-wave fused u64 DPP max
// -> parity-double-buffered s_cand[2][16] -> ONE barrier -> all waves reduce
// the <=16 candidates + readlane -> coords from LDS. Separate launches per
// layer (r10's fused chain regressed: 16-wave barriers on tiny phases).
__global__ void fps_small_kernel(const float* __restrict__ xyz,
    float* __restrict__ new_xyz, int N, int S) {
  const int b = blockIdx.x;
  const int tid = threadIdx.x;
  const int lane = tid & 63;
  const int wv = tid >> 6;                // wave id, 0..15
  const int NW = N >> 6;                  // waves per block (N in {1024,256,64})
  const float* px = xyz + (size_t)b * N * 3;
  __shared__ float sx[1024], sy[1024], sz[1024];
  __shared__ unsigned long long s_cand[2][16];
  float x = px[tid * 3 + 0], y = px[tid * 3 + 1], z = px[tid * 3 + 2];
  sx[tid] = x; sy[tid] = y; sz[tid] = z;
  float mind = 1e10f;
  float qx = px[0], qy = px[1], qz = px[2];
  if (tid == 0) {
    float* o = new_xyz + (size_t)b * S * 3;
    o[0] = qx; o[1] = qy; o[2] = qz;
  }
  __syncthreads();
  for (unsigned it = 1; it < (unsigned)S; ++it) {
    float dx = __fsub_rn(x, qx);
    float dy = __fsub_rn(y, qy);
    float dz = __fsub_rn(z, qz);
    float d = __fadd_rn(__fadd_rn(__fmul_rn(dx, dx), __fmul_rn(dy, dy)), __fmul_rn(dz, dz));
    mind = fminf(mind, d);
    unsigned long long key = ((unsigned long long)__float_as_uint(mind) << 32)
                           | (0xFFFFFFFFu - (unsigned)tid);
    key = dpp_max_u64(key);
    if (lane == 63) s_cand[it & 1u][wv] = key;
    __syncthreads();                        // the ONLY barrier per iteration
    unsigned long long k = (lane < NW) ? s_cand[it & 1u][lane] : 0ull;
    k = dpp_max_u64(k);
    unsigned klo = (unsigned)__builtin_amdgcn_readlane((int)(unsigned)k, 63);
    int last = (int)(0xFFFFFFFFu - klo);
    qx = sx[last]; qy = sy[last]; qz = sz[last];   // LDS broadcast
    if (tid == 0) {
      float* o = new_xyz + ((size_t)b * S + it) * 3;
      o[0] = qx; o[1] = qy; o[2] = qz;
    }
  }
}

// ---------------------------------------------------------------------------
// Ball query: one wave per center; take the FIRST nsample indices (ascending)
// with d2 < r2 (== nsample smallest indices, matching top_k(-key)). Pad with
// the first hit (0 if no hits). Dedicated kernel (r10's in-GEMM fusion
// regressed: half-utilized query waves + grid.y duplication).
__global__ __launch_bounds__(256) void ballquery_kernel(const float* __restrict__ xyz,
    const float* __restrict__ centers, int* __restrict__ out_idx,
    int N, int S, int nsample, float r2) {
  int gw = (blockIdx.x * blockDim.x + threadIdx.x) >> 6;
  int lane = threadIdx.x & 63;
  int b = gw / S;
  int s = gw - b * S;
  const float* px = xyz + (size_t)b * N * 3;
  const float* cp = centers + ((size_t)b * S + s) * 3;
  float cx = cp[0], cy = cp[1], cz = cp[2];
  int* out = out_idx + ((size_t)b * S + s) * nsample;
  int cnt = 0;
  int firsti = 0;
  for (int base = 0; base < N; base += WAVE) {
    int i = base + lane;
    float dx = __fsub_rn(cx, px[i * 3 + 0]);
    float dy = __fsub_rn(cy, px[i * 3 + 1]);
    float dz = __fsub_rn(cz, px[i * 3 + 2]);
    float d = __fadd_rn(__fadd_rn(__fmul_rn(dx, dx), __fmul_rn(dy, dy)), __fmul_rn(dz, dz));
    bool hit = d < r2;
    unsigned long long m = __ballot(hit);
    if (hit) {
      int slot = cnt + __popcll(m & ((1ull << lane) - 1ull));
      if (slot < nsample) out[slot] = i;
    }
    if (cnt == 0 && m) firsti = base + __ffsll((unsigned long long)m) - 1;
    cnt += __popcll(m);
    if (cnt >= nsample) break;
  }
  for (int q = cnt + lane; q < nsample; q += WAVE) out[q] = firsti;
}

// ---------------------------------------------------------------------------
// Fused tiled f32 GEMM: Y(RxCo) = normReLU(A)(RxC) @ W(CxCo).
//  - GATHER MODE (idx != nullptr; j0): A built on the fly from
//    [xyz[j]-center, feats[j]] (bit-identical __fsub_rn expression) — X0 is
//    never materialized (r9-verified).
//  - EXTREMA MODE (extmax != nullptr; j2): Y not written; per-group max AND
//    min of raw y -> monotone-mapped u32 LDS atomics -> global (G x Co).
//    f(y)=gamma*((y-mu)*rs)+beta is monotone in y => final pass picks
//    max/min by sign(gamma). Bit-exact (r9-verified).
//  - kmax dynamic K-bound (r10): skipped terms added exactly +-0 (zero-padded
//    columns) => output-identical; saves 10/16 of l0-j0's FMAs.
// R % 64 == 0 always; C/Co guarded.
#define BM 64
#define BN 64
#define BK 16
__global__ __launch_bounds__(256) void mm_fused_kernel(const float* __restrict__ A,
    const float* __restrict__ W, float* __restrict__ Y,
    float* __restrict__ st_out, const float* __restrict__ st_in,
    const float* __restrict__ g_in, const float* __restrict__ b_in,
    int R, int C, int Co, float inv_n,
    const int* __restrict__ idx, const float* __restrict__ xyz,
    const float* __restrict__ feats, const float* __restrict__ centers,
    int N, int kshift, int sshift, int ci,
    unsigned* __restrict__ extmax, unsigned* __restrict__ extmin) {
  __shared__ float As[BK][BM + 4];
  __shared__ float Bs[BK][BN + 4];
  __shared__ float s_mu[260], s_rs[260], s_g[260], s_b[260];
  __shared__ float s_sum[BN], s_sq[BN];
  __shared__ int s_idx[BM];
  __shared__ unsigned s_mx[4][BN], s_mn[4][BN];
  int r0 = blockIdx.x * BM;
  int n0 = blockIdx.y * BN;
  int tid = threadIdx.x;
  int tx = tid & 15, ty = tid >> 4;
  if (st_in) {
    for (int c = tid; c < C; c += 256) {
      float mu = st_in[c] * inv_n;
      float var = st_in[512 + c] * inv_n - mu * mu;
      s_mu[c] = mu; s_rs[c] = rsqrtf(var + 1e-5f);
      s_g[c] = g_in[c]; s_b[c] = b_in[c];
    }
  }
  if (idx && tid < BM) s_idx[tid] = idx[r0 + tid];
  if (tid < BN) { s_sum[tid] = 0.f; s_sq[tid] = 0.f; }
  if (extmax) {
    for (int t2 = tid; t2 < 4 * BN; t2 += 256) {
      ((unsigned*)s_mx)[t2] = 0u;            // < mapf(any finite/inf)
      ((unsigned*)s_mn)[t2] = 0xFFFFFFFFu;   // > mapf(any finite/inf)
    }
  }
  __syncthreads();
  float acc[4][4] = {};
  for (int k0 = 0; k0 < C; k0 += BK) {
#pragma unroll
    for (int u = 0; u < 4; ++u) {
      int lin = tid + u * 256;
      int row = lin >> 4;
      int cc = lin & 15;
      int c = k0 + cc;
      float v = 0.f;
      if (c < C) {
        if (idx) {
          int r = r0 + row;
          int g = r >> kshift;
          int bb = g >> sshift;
          int j = s_idx[row];
          if (c < 3) v = __fsub_rn(xyz[((size_t)bb * N + j) * 3 + c],
                                   centers[(size_t)g * 3 + c]);
          else       v = feats[((size_t)bb * N + j) * ci + (c - 3)];
        } else {
          v = A[(size_t)(r0 + row) * C + c];
          if (st_in) {
            v = s_g[c] * ((v - s_mu[c]) * s_rs[c]) + s_b[c];
            v = v > 0.f ? v : 0.f;
          }
        }
      }
      As[cc][row] = v;
    }
#pragma unroll
    for (int u = 0; u < 4; ++u) {
      int lin = tid + u * 256;
      int kk = lin >> 6;
      int n = lin & 63;
      int c = k0 + kk;
      Bs[kk][n] = (c < C && (n0 + n) < Co) ? W[(size_t)c * Co + n0 + n] : 0.f;
    }
    __syncthreads();
    int kmax = C - k0; if (kmax > BK) kmax = BK;
    if (kmax == BK) {
#pragma unroll
      for (int kk = 0; kk < BK; ++kk) {
        float a0[4], b0[4];
#pragma unroll
        for (int i = 0; i < 4; ++i) a0[i] = As[kk][ty * 4 + i];
#pragma unroll
        for (int jj = 0; jj < 4; ++jj) b0[jj] = Bs[kk][tx * 4 + jj];
#pragma unroll
        for (int i = 0; i < 4; ++i)
#pragma unroll
          for (int jj = 0; jj < 4; ++jj)
            acc[i][jj] = fmaf(a0[i], b0[jj], acc[i][jj]);
      }
    } else {
      for (int kk = 0; kk < kmax; ++kk) {
        float a0[4], b0[4];
#pragma unroll
        for (int i = 0; i < 4; ++i) a0[i] = As[kk][ty * 4 + i];
#pragma unroll
        for (int jj = 0; jj < 4; ++jj) b0[jj] = Bs[kk][tx * 4 + jj];
#pragma unroll
        for (int i = 0; i < 4; ++i)
#pragma unroll
          for (int jj = 0; jj < 4; ++jj)
            acc[i][jj] = fmaf(a0[i], b0[jj], acc[i][jj]);
      }
    }
    __syncthreads();
  }
  if (!extmax) {
#pragma unroll
    for (int i = 0; i < 4; ++i) {
      int r = r0 + ty * 4 + i;
#pragma unroll
      for (int jj = 0; jj < 4; ++jj) {
        int n = n0 + tx * 4 + jj;
        if (n < Co) Y[(size_t)r * Co + n] = acc[i][jj];
      }
    }
  } else {
    // per-group extrema: this thread's 4 rows (ty*4..+3) lie in ONE group
    int gi = (ty * 4) >> kshift;
#pragma unroll
    for (int jj = 0; jj < 4; ++jj) {
      float mx = acc[0][jj], mn = acc[0][jj];
#pragma unroll
      for (int i = 1; i < 4; ++i) {
        mx = fmaxf(mx, acc[i][jj]); mn = fminf(mn, acc[i][jj]);
      }
      atomicMax(&s_mx[gi][tx * 4 + jj], mapf(mx));
      atomicMin(&s_mn[gi][tx * 4 + jj], mapf(mn));
    }
  }
  // epilogue: per-column sum/sumsq of this block's tile -> LDS -> global
#pragma unroll
  for (int jj = 0; jj < 4; ++jj) {
    float cs = 0.f, cq = 0.f;
#pragma unroll
    for (int i = 0; i < 4; ++i) { float v = acc[i][jj]; cs += v; cq += v * v; }
    atomicAdd(&s_sum[tx * 4 + jj], cs);
    atomicAdd(&s_sq[tx * 4 + jj], cq);
  }
  __syncthreads();
  if (tid < BN) {
    int n = n0 + tid;
    if (n < Co) {
      atomicAdd(&st_out[n], s_sum[tid]);
      atomicAdd(&st_out[512 + n], s_sq[tid]);
    }
  }
  if (extmax) {
    int gpb = BM >> kshift;               // groups per block (2 or 4)
    if (tid < gpb * BN) {
      int gi = tid >> 6;
      int n = tid & 63;
      if (n0 + n < Co) {
        size_t o = (size_t)((r0 >> kshift) + gi) * Co + n0 + n;
        extmax[o] = s_mx[gi][n];
        extmin[o] = s_mn[gi][n];
      }
    }
  }
}

// Final pass: normalize the pre-reduced group extremum and relu. Slope of
// f(y)=gamma*((y-mu)*rs)+beta is sign(gamma) (rs>0): pick max for gamma>=0,
// min otherwise. Bit-exact vs per-element normalize-then-max (monotonicity).
__global__ __launch_bounds__(256) void norm_max_final_kernel(
    const unsigned* __restrict__ extmax, const unsigned* __restrict__ extmin,
    float* __restrict__ O, const float* __restrict__ st,
    const float* __restrict__ gamma, const float* __restrict__ beta,
    int total, int Co, float inv_n) {
  int t = blockIdx.x * blockDim.x + threadIdx.x;
  if (t >= total) return;
  int c = t & (Co - 1);
  float mu = st[c] * inv_n;
  float var = st[512 + c] * inv_n - mu * mu;
  float rs = rsqrtf(var + 1e-5f);
  float ga = gamma[c], be = beta[c];
  float y = (ga >= 0.f) ? unmapf(extmax[t]) : unmapf(extmin[t]);
  float v = ga * ((y - mu) * rs) + be;
  O[t] = v > 0.f ? v : 0.f;
}

// ---------------------------------------------------------------------------
extern "C" void kernel_launch(void* const* d_in, const int* in_sizes, int n_in,
                              void* d_out, int out_size, void* d_ws, size_t ws_size,
                              hipStream_t stream) {
  const float* pc = (const float*)d_in[0];
  float* out = (float*)d_out;
  char* wsb = (char*)d_ws;

  // ws layout: [0,1MB) ball idx; [1MB,+48KB) stats; [2MB,+512KB) fps slots;
  //            [3MB,5MB) extmax; [5MB,7MB) extmin; [8MB,42MB) bufA;
  //            [42MB,76MB) bufB
  int* ballidx = (int*)wsb;
  float* stats = (float*)(wsb + ((size_t)1 << 20));
  unsigned long long* gkey = (unsigned long long*)(wsb + ((size_t)2 << 20));
  unsigned* extmax = (unsigned*)(wsb + ((size_t)3 << 20));
  unsigned* extmin = (unsigned*)(wsb + ((size_t)5 << 20));
  float* bufA = (float*)(wsb + ((size_t)8 << 20));
  float* bufB = (float*)(wsb + ((size_t)42 << 20));

  const int B = 8;
  static const int Ns[4] = {16384, 1024, 256, 64};
  static const int Ss[4] = {1024, 256, 64, 16};
  static const int Ks[4] = {32, 32, 16, 16};
  static const int Ksh[4] = {5, 5, 4, 4};     // log2(K)
  static const int Ssh[4] = {10, 8, 6, 4};    // log2(S)
  static const double Rr[4] = {0.02, 0.04, 0.06, 0.08};
  static const int Ci[4] = {3, 64, 128, 256};
  static const int mlp[4][4] = {{6,32,32,64},{67,64,64,128},{131,128,128,256},{259,256,256,512}};
  static const size_t ox[5] = {0, 393216, 417792, 423936, 425472};
  static const size_t of[5] = {425856, 819072, 1343360, 1605504, 1736576};

  // split (131072 rows) + zero stats/slots ([1MB,3MB) = 524288 f32), fused
  init_kernel<<<(524288 + 255) / 256, 256, 0, stream>>>(pc, out + ox[0], out + of[0],
                                                        stats, B * 16384, 524288);

  for (int l = 0; l < 4; ++l) {
    const float* xyz = out + ox[l];
    const float* fts = out + of[l];
    float* nxyz = out + ox[l + 1];
    const int N = Ns[l], S = Ss[l], ci = Ci[l];
    const float r2 = (float)(Rr[l] * Rr[l]);

    if (l == 0) fps_big_multi_kernel<<<B * FPS_W, 256, 0, stream>>>(xyz, nxyz, gkey, N, S);
    else        fps_small_kernel<<<B, N, 0, stream>>>(xyz, nxyz, N, S);

    ballquery_kernel<<<(B * S) / 4, 256, 0, stream>>>(xyz, nxyz, ballidx, N, S, Ks[l], r2);

    const int R = B * S * Ks[l];
    const float inv_n = 1.0f / (float)R;
    float* X = bufA; float* Y = bufB;
    const float* prev_st = nullptr;
    const float* prev_g = nullptr;
    const float* prev_b = nullptr;
    for (int j = 0; j < 3; ++j) {
      const int cin = mlp[l][j], cout = mlp[l][j + 1];
      const float* Wt = (const float*)d_in[1 + (l * 3 + j) * 3 + 0];
      const float* Ga = (const float*)d_in[1 + (l * 3 + j) * 3 + 1];
      const float* Be = (const float*)d_in[1 + (l * 3 + j) * 3 + 2];
      float* st = stats + (size_t)(l * 3 + j) * 1024;
      const bool last = (j == 2);
      dim3 grid(R / 64, (cout + 63) / 64);
      mm_fused_kernel<<<grid, 256, 0, stream>>>(
          (j == 0) ? nullptr : X, Wt, last ? nullptr : Y, st,
          prev_st, prev_g, prev_b, R, cin, cout, inv_n,
          (j == 0) ? ballidx : nullptr, xyz, fts, nxyz,
          N, Ksh[l], Ssh[l], ci,
          last ? extmax : nullptr, last ? extmin : nullptr);
      if (!last) {
        prev_st = st; prev_g = Ga; prev_b = Be;
        float* tswap = X; X = Y; Y = tswap;
      } else {
        int G = B * S;
        int tot = G * cout;
        norm_max_final_kernel<<<(tot + 255) / 256, 256, 0, stream>>>(
            extmax, extmin, out + of[l + 1], st, Ga, Be, tot, cout, inv_n);
      }
    }
  }
}